// Round 8
// baseline (357.052 us; speedup 1.0000x reference)
//
#include <hip/hip_runtime.h>

typedef short short8 __attribute__((ext_vector_type(8)));
typedef float float4v __attribute__((ext_vector_type(4)));
typedef int int4v __attribute__((ext_vector_type(4)));
typedef unsigned int uint2v __attribute__((ext_vector_type(2)));
typedef unsigned int uint4v __attribute__((ext_vector_type(4)));
typedef unsigned short ushort_t;

#define INV_EXT (1.0f / 0.048f)
#define EXT 0.048f
#define HN 32
#define KK 15
#define CIN 64
#define COUT 64
#define PB 16      /* points per tile */
#define KDIM 1024  /* padded 16 k' * 64 c, order defined by j-map */
#define NSLOT 16   /* stats atomic slots */
#define CELL_INV 64.0f   /* cell grid [-8,8) in 1024 steps, CS = 2^-6 exact */
#define GRIDF 960  /* fused grid: <= 0.94 * (256 CU x 4 blocks @ 35.6 KB LDS) */
#define NGRP 30    /* barrier tree: 30 leaves x 32 blocks */

// round-half-up bf16
__device__ inline ushort_t rh_bf16(float f) {
    return (ushort_t)((__float_as_uint(f) + 0x8000u) >> 16);
}
__device__ inline unsigned pk_bf16(float a, float b) {
    unsigned ua = __float_as_uint(a) + 0x8000u;
    unsigned ub = __float_as_uint(b) + 0x8000u;
    return (ua >> 16) | (ub & 0xffff0000u);
}
// cell index; clamping only shrinks |dc| -> false-pass only (skip stays exact)
__device__ inline int cellq(float v) {
    return (int)fminf(1023.f, fmaxf(0.f, (v + 8.f) * CELL_INV));
}
__device__ inline int imax3(int a, int b, int c) {
    int m = a > b ? a : b; return m > c ? m : c;
}
__device__ inline int iabs(int a) { return a < 0 ? -a : a; }

union Frag8 { short8 s; unsigned u[4]; };

// wtS element index: row p, kd-slot j; 16B-granule XOR swizzle by p (R0-proven)
__device__ inline int wtJ(int p, int j) {
    return p * KDIM + ((((j >> 3) ^ (p & 7)) << 3) | (j & 7));
}

// one-shot 2-level grid barrier (device-scope atomics; counters pre-zeroed by prep)
__device__ inline void grid_barrier(int* bar) {
    __threadfence();
    __syncthreads();
    if (threadIdx.x == 0) {
        int g = blockIdx.x >> 5;                       // 30 groups of 32
        if (atomicAdd(&bar[g], 1) == 31)               // last of group
            atomicAdd(&bar[NGRP], 1);                  // root
        while (atomicAdd(&bar[NGRP], 0) < NGRP)
            __builtin_amdgcn_s_sleep(2);
    }
    __syncthreads();
    __threadfence();
}

// ============ K1: fused screen+compute (persistent) + barrier + norm ==========
// R7 lesson: splitting kernels added cost; occupancy was never the screen's
// limit. This round removes dispatch boundaries instead: one resident grid
// does per-tile screen+compute (R6-proven body), one ~2us tree barrier, then
// stats+norm. 2 dispatches total (prep + this).
template <bool CODE>
__global__ __launch_bounds__(256, 4)
void fused_kernel(const float* __restrict__ q_pts,
                  const float* __restrict__ s_pts,
                  const int*   __restrict__ inds,
                  const float* __restrict__ x,
                  const float* __restrict__ kpts,
                  const ushort_t* __restrict__ W3,   // [128 kd-octets][64 d][8] bf16
                  const unsigned* __restrict__ code, // [N] packed 3x10b cells
                  float* __restrict__ out,
                  float* __restrict__ sums,
                  unsigned* __restrict__ mask,
                  int* __restrict__ bar, int N, int nblk)
{
    __shared__ __align__(16) short wtS[PB * KDIM];  // 32 KB; rows double as coord scratch
    __shared__ int indS[PB * HN];                   // 2 KB
    __shared__ unsigned actS[PB];                   // 64 B
    __shared__ float nmS[192];                      // 768 B: mean/inv/cz

    const int t = threadIdx.x;
    const int lane = t & 63;
    const int wid = t >> 6;
    const int l15 = lane & 15;
    const int q = lane >> 4;
    float* fp = (float*)wtS;   // coords: fp[p*512 + c*32 + h]

    // ---- screen bound: b = max_k |kp_k| + ext + eps (overestimate-only) ----
    float bound2; int CL;
    {
        int ki = l15 < KK ? l15 : 0;
        float bx = kpts[ki * 3 + 0], by = kpts[ki * 3 + 1], bz = kpts[ki * 3 + 2];
        float kn = l15 < KK ? __builtin_amdgcn_sqrtf(fmaf(bx, bx, fmaf(by, by, bz * bz)))
                            : 0.f;
        kn = fmaxf(kn, __shfl_xor(kn, 1));
        kn = fmaxf(kn, __shfl_xor(kn, 2));
        kn = fmaxf(kn, __shfl_xor(kn, 4));
        kn = fmaxf(kn, __shfl_xor(kn, 8));
        float b = kn + EXT + 1e-4f;
        bound2 = b * b;
        CL = (int)(b * CELL_INV) + 1;   // floor+1 >= ceil -> over-pass only
    }
    const int d0 = wid * 16;
    const ushort_t* wb = W3 + (size_t)q * 512 + (d0 + l15) * 8;

    // ================= phase BC: per-tile screen + compute =================
    for (int tile = blockIdx.x; tile < nblk; tile += GRIDF) {
        __syncthreads();               // prev tile's LDS reads done before overwrite
        const int n0 = tile * PB;

        // ---- phase 0: coarse code screen; exact fetch+test only on pass ----
        for (int it = 0; it < 2; ++it) {
            int pi = t + it * 256;          // (p,h)
            int p = pi >> 5, h = pi & 31;
            int n = n0 + p;
            float sx = 1e9f, sy = 1e9f, sz = 1e9f; int idx = 0;
            float dd = 1e18f;
            if (n < N) {
                idx = inds[n * HN + h];
                float qx = q_pts[n * 3 + 0];
                float qy = q_pts[n * 3 + 1];
                float qz = q_pts[n * 3 + 2];
                bool pass = true;
                if constexpr (CODE) {
                    unsigned cs = code[idx];           // ONE random dword per pair
                    int dcx = iabs((int)(cs & 1023u)         - cellq(qx));
                    int dcy = iabs((int)((cs >> 10) & 1023u) - cellq(qy));
                    int dcz = iabs((int)((cs >> 20) & 1023u) - cellq(qz));
                    pass = imax3(dcx, dcy, dcz) <= CL; // ~3e-4 of pairs
                }
                if (pass) {
                    const float* sp = s_pts + (size_t)idx * 3;
                    sx = sp[0]; sy = sp[1]; sz = sp[2];
                    float ex = sx - qx, ey = sy - qy, ez = sz - qz;
                    dd = fmaf(ex, ex, fmaf(ey, ey, ez * ez));
                }
            }
            indS[pi] = idx;
            fp[p * 512 + h]      = sx;    // coarse-fail keeps sentinel -> w = 0
            fp[p * 512 + 32 + h] = sy;
            fp[p * 512 + 64 + h] = sz;
            unsigned long long bal = __ballot(dd < bound2);
            if (lane == 0)  actS[p] = (unsigned)(bal & 0xffffffffull);
            if (lane == 32) actS[p] = (unsigned)(bal >> 32);
        }
        __syncthreads();

        unsigned long long bb = __ballot(actS[l15] != 0);
        const unsigned ba = (unsigned)bb & 0xffffu;
        if (t == 0) mask[tile] = ba;      // unique writer, no atomic, no pre-zero
        if (ba == 0) continue;            // ~94% of tiles
        const int pbits = (ba >> (wid * 4)) & 0xf;

        // ---- phase 1: A-fragments for this wave's ACTIVE points only ----
        Frag8 afrag[4];
        if (pbits) {
            int kidx = l15 < KK ? l15 : 0;
            float kx = kpts[kidx * 3 + 0];
            float ky = kpts[kidx * 3 + 1];
            float kz = kpts[kidx * 3 + 2];
            if (l15 >= KK) { kx = 3e4f; ky = 3e4f; kz = 3e4f; }  // pad kp -> w = 0
#pragma unroll
            for (int i = 0; i < 4; ++i) {
                if (!(pbits & (1 << i))) continue;
                int p = wid * 4 + i;
                int n = n0 + p;
                int nc = n < N ? n : 0;
                float qkx = q_pts[nc * 3 + 0] + kx;   // s - (q+kp): err ~6e-8 << d
                float qky = q_pts[nc * 3 + 1] + ky;
                float qkz = q_pts[nc * 3 + 2] + kz;
                int base = p * 512 + q * 8;
                float4v x0 = *(float4v*)&fp[base],      x1 = *(float4v*)&fp[base + 4];
                float4v y0 = *(float4v*)&fp[base + 32], y1 = *(float4v*)&fp[base + 36];
                float4v z0 = *(float4v*)&fp[base + 64], z1 = *(float4v*)&fp[base + 68];
                float w[8];
#pragma unroll
                for (int j = 0; j < 8; ++j) {
                    float dx = (j < 4 ? x0[j & 3] : x1[j & 3]) - qkx;
                    float dy = (j < 4 ? y0[j & 3] : y1[j & 3]) - qky;
                    float dz = (j < 4 ? z0[j & 3] : z1[j & 3]) - qkz;
                    float d = __builtin_amdgcn_sqrtf(fmaf(dx, dx, fmaf(dy, dy, dz * dz)));
                    w[j] = fmaxf(fmaf(d, -INV_EXT, 1.0f), 0.0f);
                }
#pragma unroll
                for (int jj = 0; jj < 4; ++jj)
                    afrag[i].u[jj] = pk_bf16(w[2 * jj], w[2 * jj + 1]);
            }
        }

        // ---- phase 2: active points -> gather x + MFMA; inactive -> zero row ----
#pragma unroll
        for (int i = 0; i < 4; ++i) {
            int p = wid * 4 + i;
            if (pbits & (1 << i)) {
                int ibase = p * HN + q * 8;
                int4v ia = *(int4v*)&indS[ibase];       // broadcast b128
                int4v ib = *(int4v*)&indS[ibase + 4];
                const float* rpf[8];
#pragma unroll
                for (int j = 0; j < 8; ++j) {
                    int idx = j < 4 ? ia[j] : ib[j - 4];
                    rpf[j] = x + (size_t)idx * CIN;
                }
#pragma unroll
                for (int ct = 0; ct < 4; ++ct) {
                    short8 b;
#pragma unroll
                    for (int j = 0; j < 8; ++j)
                        b[j] = (short)rh_bf16(rpf[j][ct * 16 + l15]);
                    float4v acc = {0.f, 0.f, 0.f, 0.f};
                    acc = __builtin_amdgcn_mfma_f32_16x16x32_bf16(afrag[i].s, b, acc, 0, 0, 0);
                    // D row m = k' = q*4+r, col n = c = ct*16+l15.
                    // kd-slot j = quad*4 + r, quad = l15 + 16*(q^ct) + 64*ct
                    uint2v v2;
                    v2[0] = pk_bf16(acc[0], acc[1]);
                    v2[1] = pk_bf16(acc[2], acc[3]);
                    int quad = l15 + 16 * (q ^ ct) + 64 * ct;
                    *(uint2v*)&wtS[wtJ(p, quad * 4)] = v2;
                }
            } else {
                uint4v z = {0u, 0u, 0u, 0u};
                *(uint4v*)&wtS[p * KDIM + lane * 16]     = z;
                *(uint4v*)&wtS[p * KDIM + lane * 16 + 8] = z;
            }
        }
        __syncthreads();

        // ---- phase 3: OUT[16p x 64d] = wt @ W3 ----
        float4v acc3 = {0.f, 0.f, 0.f, 0.f};
#pragma unroll 8
        for (int s = 0; s < 32; ++s) {
            short8 a = *(short8*)&wtS[wtJ(l15, s * 32 + q * 8)];
            short8 bb2 = *(const short8*)(wb + (size_t)s * 2048);
            acc3 = __builtin_amdgcn_mfma_f32_16x16x32_bf16(a, bb2, acc3, 0, 0, 0);
        }

        // ---- epilogue: store + stats for ACTIVE rows only ----
        float s1 = 0.f, s2 = 0.f;
#pragma unroll
        for (int r = 0; r < 4; ++r) {
            int p = q * 4 + r;
            int n = n0 + p;
            float v = acc3[r];
            if (((ba >> p) & 1) && n < N) {
                out[n * COUT + d0 + l15] = v;
                s1 += v; s2 += v * v;
            }
        }
        s1 += __shfl_xor(s1, 16); s2 += __shfl_xor(s2, 16);
        s1 += __shfl_xor(s1, 32); s2 += __shfl_xor(s2, 32);
        if (q == 0) {
            int slot = tile & (NSLOT - 1);
            atomicAdd(&sums[slot * 128 + d0 + l15], s1);
            atomicAdd(&sums[slot * 128 + 64 + d0 + l15], s2);
        }
    }

    // ================= barrier: all sums/mask/out visible =================
    grid_barrier(bar);

    // ================= phase D: stats + instance-norm + LeakyReLU =========
    if (t < 64) {
        float s1 = 0.f, s2 = 0.f;
#pragma unroll
        for (int sl = 0; sl < NSLOT; ++sl) {
            s1 += sums[sl * 128 + t];
            s2 += sums[sl * 128 + 64 + t];
        }
        float invN = 1.0f / (float)N;
        float mean = s1 * invN;
        float var = fmaxf(s2 * invN - mean * mean, 0.f);
        float inv = rsqrtf(var + 1e-5f);
        nmS[t] = mean;
        nmS[64 + t] = inv;
        float cz = (0.f - mean) * inv;
        nmS[128 + t] = cz >= 0.f ? cz : 0.1f * cz;
    }
    __syncthreads();
    long total = (long)N * 16;   // float4 chunks
    for (long i = (long)blockIdx.x * 256 + t; i < total; i += (long)GRIDF * 256) {
        int cb = (int)((i * 4) & 63);
        long n = i >> 4;
        unsigned mw = mask[n >> 4];
        float4v v;
        if ((mw >> ((int)n & 15)) & 1) {
            v = *(float4v*)&out[i * 4];
#pragma unroll
            for (int j = 0; j < 4; ++j) {
                float val = (v[j] - nmS[cb + j]) * nmS[64 + cb + j];
                v[j] = val >= 0.f ? val : 0.1f * val;
            }
        } else {
#pragma unroll
            for (int j = 0; j < 4; ++j) v[j] = nmS[128 + cb + j];
        }
        *(float4v*)&out[i * 4] = v;
    }
}

// ===== K0: prep (zero sums+barrier, W->W3 blocked layout, s_pts->codes) =======
template <bool CODE>
__global__ void prep_kernel(const float* __restrict__ W,
                            const float* __restrict__ s_pts,
                            float* sums, ushort_t* W3, unsigned* code,
                            int* bar, int N)
{
    int gt = blockIdx.x * 256 + threadIdx.x;
    int stride = gridDim.x * 256;
    if (gt < NSLOT * 128) sums[gt] = 0.f;
    if (gt < NGRP + 1) bar[gt] = 0;
    for (int i = gt; i < COUT * KDIM; i += stride) {
        int d = (i >> 3) & 63;
        int j = ((i >> 9) << 3) | (i & 7);  // kd-slot
        int quad = j >> 2, r = j & 3;
        int l15 = quad & 15, e = (quad >> 4) & 3, ct = quad >> 6;
        int k = (e ^ ct) * 4 + r, c = ct * 16 + l15;
        W3[i] = (k < KK) ? rh_bf16(W[(k * CIN + c) * COUT + d]) : (ushort_t)0;
    }
    if constexpr (CODE) {
        for (int i = gt; i < N; i += stride) {
            const float* sp = s_pts + (size_t)i * 3;
            code[i] = (unsigned)cellq(sp[0])
                    | ((unsigned)cellq(sp[1]) << 10)
                    | ((unsigned)cellq(sp[2]) << 20);
        }
    }
}

extern "C" void kernel_launch(void* const* d_in, const int* in_sizes, int n_in,
                              void* d_out, int out_size, void* d_ws, size_t ws_size,
                              hipStream_t stream)
{
    const float* q  = (const float*)d_in[0];
    const float* s  = (const float*)d_in[1];
    const int* inds = (const int*)d_in[2];
    const float* x  = (const float*)d_in[3];
    const float* kp = (const float*)d_in[4];
    const float* W  = (const float*)d_in[5];
    float* out = (float*)d_out;
    int N = in_sizes[0] / 3;

    int nblk = (N + PB - 1) / PB;
    // workspace layout
    float* sums    = (float*)d_ws;                                 // 8 KB
    ushort_t* W3   = (ushort_t*)((char*)d_ws + 8192);              // 128 KB
    size_t mask_off = 8192 + 131072;
    unsigned* mask = (unsigned*)((char*)d_ws + mask_off);          // nblk*4
    size_t bar_off  = mask_off + (((size_t)nblk * 4 + 255) & ~(size_t)255);
    int* bar       = (int*)((char*)d_ws + bar_off);                // 128 B
    size_t code_off = bar_off + 256;
    unsigned* code = (unsigned*)((char*)d_ws + code_off);          // N*4
    bool useCode = ws_size >= code_off + (size_t)N * 4;

    if (useCode) {
        prep_kernel<true ><<<256, 256, 0, stream>>>(W, s, sums, W3, code, bar, N);
        fused_kernel<true ><<<GRIDF, 256, 0, stream>>>(q, s, inds, x, kp, W3, code,
                                                       out, sums, mask, bar, N, nblk);
    } else {
        prep_kernel<false><<<256, 256, 0, stream>>>(W, s, sums, W3, code, bar, N);
        fused_kernel<false><<<GRIDF, 256, 0, stream>>>(q, s, inds, x, kp, W3, code,
                                                       out, sums, mask, bar, N, nblk);
    }
}

// Round 9
// 120.917 us; speedup vs baseline: 2.9529x; 2.9529x over previous
//
#include <hip/hip_runtime.h>

typedef short short8 __attribute__((ext_vector_type(8)));
typedef float float4v __attribute__((ext_vector_type(4)));
typedef int int4v __attribute__((ext_vector_type(4)));
typedef unsigned int uint2v __attribute__((ext_vector_type(2)));
typedef unsigned int uint4v __attribute__((ext_vector_type(4)));
typedef unsigned short ushort_t;

#define INV_EXT (1.0f / 0.048f)
#define EXT 0.048f
#define HN 32
#define KK 15
#define CIN 64
#define COUT 64
#define PB 16      /* points per block */
#define KDIM 1024  /* padded 16 k' * 64 c, order defined by j-map */
#define NSLOT 16   /* stats atomic slots */

// round-half-up bf16
__device__ inline ushort_t rh_bf16(float f) {
    return (ushort_t)((__float_as_uint(f) + 0x8000u) >> 16);
}
// pack two floats into two bf16 in one u32 (lo = a, hi = b)
__device__ inline unsigned pk_bf16(float a, float b) {
    unsigned ua = __float_as_uint(a) + 0x8000u;
    unsigned ub = __float_as_uint(b) + 0x8000u;
    return (ua >> 16) | (ub & 0xffff0000u);
}

union Frag8 { short8 s; unsigned u[4]; };

// wtS element index: row p (1024 shorts), logical kd-slot j. 16B-granule XOR
// swizzle by p so phase-3 reads (p = lane&15) spread across banks. (R0-proven.)
__device__ inline int wtJ(int p, int j) {
    return p * KDIM + ((((j >> 3) ^ (p & 7)) << 3) | (j & 7));
}

// ================= K1: main KPConv, triangle-inequality screen in phase 0 =====
// Best-measured configuration of the session (121.0 us). Sparsity: random
// neighbors sit at |diff| ~ 1.4 vs reach max|kp|+ext ~ 0.11 -> ~99.6% of pairs
// have ALL 16 influences exactly 0 (triangle inequality: |diff| >= max|kp|+ext
// => |diff-kp| >= ext for every kp). One sq-test per (point,neighbor) during
// phase 0; ~94% of blocks exit after phase 0. Active path = R0-verified maps.
__global__ __launch_bounds__(256, 4)
void kpconv_main(const float* __restrict__ q_pts,
                 const float* __restrict__ s_pts,
                 const int*   __restrict__ inds,
                 const float* __restrict__ x,
                 const float* __restrict__ kpts,
                 const ushort_t* __restrict__ W3,   // [128 kd-octets][64 d][8] bf16
                 float* __restrict__ out,
                 float* __restrict__ sums,
                 unsigned* __restrict__ mask, int N)
{
    __shared__ __align__(16) short wtS[PB * KDIM];  // 32 KB; rows double as coord scratch
    __shared__ int indS[PB * HN];                   // 2 KB
    __shared__ unsigned actS[PB];                   // per-point activity (lane ballots)

    const int t = threadIdx.x;
    const int n0 = blockIdx.x * PB;
    const int lane = t & 63;
    const int wid = t >> 6;
    const int l15 = lane & 15;
    const int q = lane >> 4;

    float* fp = (float*)wtS;   // coords: fp[p*512 + c*32 + h] (384 B of 2 KB row)

    // ---- screen bound: (max_k |kp_k| + ext + eps)^2, wave-computed ----
    float bound2;
    {
        int ki = l15 < KK ? l15 : 0;
        float bx = kpts[ki * 3 + 0], by = kpts[ki * 3 + 1], bz = kpts[ki * 3 + 2];
        float kn = l15 < KK ? __builtin_amdgcn_sqrtf(fmaf(bx, bx, fmaf(by, by, bz * bz)))
                            : 0.f;
        kn = fmaxf(kn, __shfl_xor(kn, 1));
        kn = fmaxf(kn, __shfl_xor(kn, 2));
        kn = fmaxf(kn, __shfl_xor(kn, 4));
        kn = fmaxf(kn, __shfl_xor(kn, 8));
        float b = kn + EXT + 1e-4f;      // overestimate-only margin: skip stays exact
        bound2 = b * b;
    }

    // ---- phase 0: gather coords + indices, per-pair screen, per-point ballot ----
    for (int it = 0; it < 2; ++it) {
        int pi = t + it * 256;          // (p,h)
        int p = pi >> 5, h = pi & 31;
        int n = n0 + p;
        float sx = 1e9f, sy = 1e9f, sz = 1e9f; int idx = 0;
        float dd = 1e18f;
        if (n < N) {
            idx = inds[n * HN + h];
            const float* sp = s_pts + (size_t)idx * 3;
            sx = sp[0]; sy = sp[1]; sz = sp[2];
            float ex = sx - q_pts[n * 3 + 0];
            float ey = sy - q_pts[n * 3 + 1];
            float ez = sz - q_pts[n * 3 + 2];
            dd = fmaf(ex, ex, fmaf(ey, ey, ez * ez));
        }
        indS[pi] = idx;
        fp[p * 512 + h]      = sx;
        fp[p * 512 + 32 + h] = sy;
        fp[p * 512 + 64 + h] = sz;
        unsigned long long bal = __ballot(dd < bound2);
        if (lane == 0)  actS[p] = (unsigned)(bal & 0xffffffffull);
        if (lane == 32) actS[p] = (unsigned)(bal >> 32);
    }
    __syncthreads();

    // ---- block/point activity masks (uniform across waves) ----
    unsigned long long bb = __ballot(actS[l15] != 0);
    const unsigned ba = (unsigned)bb & 0xffffu;
    if (t == 0) mask[blockIdx.x] = ba;
    if (ba == 0) return;    // ~94% of blocks: done. norm writes their rows.
    const int pbits = (ba >> (wid * 4)) & 0xf;

    // ---- phase 1: A-fragments for this wave's ACTIVE points only ----
    Frag8 afrag[4];
    if (pbits) {
        int kidx = l15 < KK ? l15 : 0;
        float kx = kpts[kidx * 3 + 0];
        float ky = kpts[kidx * 3 + 1];
        float kz = kpts[kidx * 3 + 2];
        if (l15 >= KK) { kx = 3e4f; ky = 3e4f; kz = 3e4f; }  // pad kp -> w = 0
#pragma unroll
        for (int i = 0; i < 4; ++i) {
            if (!(pbits & (1 << i))) continue;
            int p = wid * 4 + i;
            int n = n0 + p;
            int nc = n < N ? n : 0;
            float qkx = q_pts[nc * 3 + 0] + kx;   // s - (q+kp): err ~6e-8 << d
            float qky = q_pts[nc * 3 + 1] + ky;
            float qkz = q_pts[nc * 3 + 2] + kz;
            int base = p * 512 + q * 8;
            float4v x0 = *(float4v*)&fp[base],      x1 = *(float4v*)&fp[base + 4];
            float4v y0 = *(float4v*)&fp[base + 32], y1 = *(float4v*)&fp[base + 36];
            float4v z0 = *(float4v*)&fp[base + 64], z1 = *(float4v*)&fp[base + 68];
            float w[8];
#pragma unroll
            for (int j = 0; j < 8; ++j) {
                float dx = (j < 4 ? x0[j & 3] : x1[j & 3]) - qkx;
                float dy = (j < 4 ? y0[j & 3] : y1[j & 3]) - qky;
                float dz = (j < 4 ? z0[j & 3] : z1[j & 3]) - qkz;
                float d = __builtin_amdgcn_sqrtf(fmaf(dx, dx, fmaf(dy, dy, dz * dz)));
                w[j] = fmaxf(fmaf(d, -INV_EXT, 1.0f), 0.0f);
            }
#pragma unroll
            for (int jj = 0; jj < 4; ++jj)
                afrag[i].u[jj] = pk_bf16(w[2 * jj], w[2 * jj + 1]);
        }
    }

    // ---- phase 2: active points -> gather x + MFMA; inactive -> zero wtS row ----
#pragma unroll
    for (int i = 0; i < 4; ++i) {
        int p = wid * 4 + i;
        if (pbits & (1 << i)) {
            int ibase = p * HN + q * 8;
            int4v ia = *(int4v*)&indS[ibase];       // broadcast b128
            int4v ib = *(int4v*)&indS[ibase + 4];
            const float* rpf[8];
#pragma unroll
            for (int j = 0; j < 8; ++j) {
                int idx = j < 4 ? ia[j] : ib[j - 4];
                rpf[j] = x + (size_t)idx * CIN;
            }
#pragma unroll
            for (int ct = 0; ct < 4; ++ct) {
                short8 b;
#pragma unroll
                for (int j = 0; j < 8; ++j)
                    b[j] = (short)rh_bf16(rpf[j][ct * 16 + l15]);
                float4v acc = {0.f, 0.f, 0.f, 0.f};
                acc = __builtin_amdgcn_mfma_f32_16x16x32_bf16(afrag[i].s, b, acc, 0, 0, 0);
                // D row m = k' = q*4+r, col n = c = ct*16+l15.
                // kd-slot j = quad*4 + r, quad = l15 + 16*(q^ct) + 64*ct
                uint2v v2;
                v2[0] = pk_bf16(acc[0], acc[1]);
                v2[1] = pk_bf16(acc[2], acc[3]);
                int quad = l15 + 16 * (q ^ ct) + 64 * ct;
                *(uint2v*)&wtS[wtJ(p, quad * 4)] = v2;
            }
        } else {
            // zero the 2 KB row: 64 lanes x 32 B (swizzle-agnostic: zeros)
            uint4v z = {0u, 0u, 0u, 0u};
            *(uint4v*)&wtS[p * KDIM + lane * 16]     = z;
            *(uint4v*)&wtS[p * KDIM + lane * 16 + 8] = z;
        }
    }
    __syncthreads();

    // ---- phase 3: OUT[16p x 64d] = wt[16p x 1024j] @ W3[1024j x 64d] ----
    const int d0 = wid * 16;
    float4v acc3 = {0.f, 0.f, 0.f, 0.f};
    const ushort_t* wb = W3 + (size_t)q * 512 + (d0 + l15) * 8;
#pragma unroll 8
    for (int s = 0; s < 32; ++s) {
        short8 a = *(short8*)&wtS[wtJ(l15, s * 32 + q * 8)];
        short8 bb2 = *(const short8*)(wb + (size_t)s * 2048);
        acc3 = __builtin_amdgcn_mfma_f32_16x16x32_bf16(a, bb2, acc3, 0, 0, 0);
    }

    // ---- epilogue: store + stats for ACTIVE rows only ----
    {
        float s1 = 0.f, s2 = 0.f;
#pragma unroll
        for (int r = 0; r < 4; ++r) {
            int p = q * 4 + r;
            int n = n0 + p;
            float v = acc3[r];
            if (((ba >> p) & 1) && n < N) {
                out[n * COUT + d0 + l15] = v;
                s1 += v; s2 += v * v;
            }
        }
        s1 += __shfl_xor(s1, 16); s2 += __shfl_xor(s2, 16);
        s1 += __shfl_xor(s1, 32); s2 += __shfl_xor(s2, 32);
        if (q == 0) {
            int slot = blockIdx.x & (NSLOT - 1);
            atomicAdd(&sums[slot * 128 + d0 + l15], s1);
            atomicAdd(&sums[slot * 128 + 64 + d0 + l15], s2);
        }
    }
}

// ================= K0: prep (zero stats, W->W3 blocked layout) ================
__global__ void prep_kernel(const float* __restrict__ W, float* sums, ushort_t* W3)
{
    int gt = blockIdx.x * 256 + threadIdx.x;
    int stride = gridDim.x * 256;
    if (gt < NSLOT * 128) sums[gt] = 0.f;
    for (int i = gt; i < COUT * KDIM; i += stride) {
        int d = (i >> 3) & 63;
        int j = ((i >> 9) << 3) | (i & 7);  // kd-slot
        int quad = j >> 2, r = j & 3;
        int l15 = quad & 15, e = (quad >> 4) & 3, ct = quad >> 6;
        int k = (e ^ ct) * 4 + r, c = ct * 16 + l15;
        W3[i] = (k < KK) ? rh_bf16(W[(k * CIN + c) * COUT + d]) : (ushort_t)0;
    }
}

// ====== K2: reduce slots + instance-norm + LeakyReLU (mask-aware) =============
// Inactive rows (pre-norm value exactly 0, never written by main) get the
// per-channel constant leaky((0-mean)*inv) with NO read of out.
__global__ void norm_kernel(float* __restrict__ out, const float* __restrict__ sums,
                            const unsigned* __restrict__ mask, int N)
{
    __shared__ float meanS[64], invS[64], czS[64];
    int t = threadIdx.x;
    if (t < 64) {
        float s1 = 0.f, s2 = 0.f;
#pragma unroll
        for (int sl = 0; sl < NSLOT; ++sl) {
            s1 += sums[sl * 128 + t];
            s2 += sums[sl * 128 + 64 + t];
        }
        float invN = 1.0f / (float)N;
        float mean = s1 * invN;
        float var = fmaxf(s2 * invN - mean * mean, 0.f);
        float inv = rsqrtf(var + 1e-5f);
        meanS[t] = mean;
        invS[t] = inv;
        float cz = (0.f - mean) * inv;
        czS[t] = cz >= 0.f ? cz : 0.1f * cz;
    }
    __syncthreads();
    long total = (long)N * 16;   // float4 chunks
    for (long i = (long)blockIdx.x * blockDim.x + t; i < total;
         i += (long)gridDim.x * blockDim.x) {
        int cb = (int)((i * 4) & 63);
        long n = i >> 4;
        unsigned mw = mask[n >> 4];
        float4v v;
        if ((mw >> ((int)n & 15)) & 1) {
            v = *(float4v*)&out[i * 4];
#pragma unroll
            for (int j = 0; j < 4; ++j) {
                float val = (v[j] - meanS[cb + j]) * invS[cb + j];
                v[j] = val >= 0.f ? val : 0.1f * val;
            }
        } else {
#pragma unroll
            for (int j = 0; j < 4; ++j) v[j] = czS[cb + j];
        }
        *(float4v*)&out[i * 4] = v;
    }
}

extern "C" void kernel_launch(void* const* d_in, const int* in_sizes, int n_in,
                              void* d_out, int out_size, void* d_ws, size_t ws_size,
                              hipStream_t stream)
{
    const float* q  = (const float*)d_in[0];
    const float* s  = (const float*)d_in[1];
    const int* inds = (const int*)d_in[2];
    const float* x  = (const float*)d_in[3];
    const float* kp = (const float*)d_in[4];
    const float* W  = (const float*)d_in[5];
    float* out = (float*)d_out;
    int N = in_sizes[0] / 3;

    float* sums  = (float*)d_ws;                                  // 8 KB
    ushort_t* W3 = (ushort_t*)((char*)d_ws + 8192);               // 128 KB
    unsigned* mask = (unsigned*)((char*)d_ws + 8192 + 131072);    // nblk * 4 B

    int nblk = (N + PB - 1) / PB;
    prep_kernel<<<256, 256, 0, stream>>>(W, sums, W3);
    kpconv_main<<<nblk, 256, 0, stream>>>(q, s, inds, x, kp, W3, out, sums, mask, N);
    norm_kernel<<<2048, 256, 0, stream>>>(out, sums, mask, N);
}